// Round 5
// baseline (405.502 us; speedup 1.0000x reference)
//
#include <hip/hip_runtime.h>
#include <math.h>

#define DD   128      // hidden dim
#define LL   32       // sequence length
#define MS   16       // sequences per block
#define NT   512      // threads per block (8 waves)
#define NSEQ 8192     // B*S
#define XHP  264      // xh row pitch in ushorts (256 data + 8 pad; 528 B)
#define OLP  36       // outl pitch in floats

typedef short bf16x8 __attribute__((ext_vector_type(8)));   // 8 bf16 = 4 VGPRs
typedef float f32x4  __attribute__((ext_vector_type(4)));

__device__ __forceinline__ unsigned short f2bf(float f) {
    unsigned u = __float_as_uint(f);
    u += 0x7fffu + ((u >> 16) & 1u);          // round-to-nearest-even
    return (unsigned short)(u >> 16);
}

#if __has_builtin(__builtin_amdgcn_cvt_pk_bf16_f32)
typedef __bf16 bf16x2_t __attribute__((ext_vector_type(2)));
__device__ __forceinline__ unsigned pack2(float a, float b) {
    union { bf16x2_t v; unsigned u; } c;
    c.v = __builtin_amdgcn_cvt_pk_bf16_f32(a, b);
    return c.u;
}
#else
__device__ __forceinline__ unsigned pack2(float a, float b) {
    return (unsigned)f2bf(a) | ((unsigned)f2bf(b) << 16);
}
#endif

__device__ __forceinline__ void pack8(float4 a, float4 b, unsigned short* dst) {
    union { unsigned u[4]; bf16x8 v; } pk;
    pk.u[0] = pack2(a.x, a.y); pk.u[1] = pack2(a.z, a.w);
    pk.u[2] = pack2(b.x, b.y); pk.u[3] = pack2(b.z, b.w);
    *(bf16x8*)dst = pk.v;
}

__device__ __forceinline__ float fast_rcp(float x) {
    return __builtin_amdgcn_rcpf(x);
}

// ---------------------------------------------------------------------------
// Prep: swizzle W_ih/W_hh into MFMA B-operand fragment order, bf16.
//   ct 0..15 : r,z gates  g=ct*16+n,        k=kk*32+q*8+j (K=256 concat x|h)
//   ct 16..23: n-gate x-side, kk 0..3, k in [0,128)   (W_ih)
//   ct 24..31: n-gate h-side, kk 4..7, k-128 in [0,128) (W_hh)
// ---------------------------------------------------------------------------
__global__ void prep_weights(const float* __restrict__ Wih,
                             const float* __restrict__ Whh,
                             unsigned short* __restrict__ Wfrag) {
    int idx = blockIdx.x * blockDim.x + threadIdx.x;   // 0 .. 131071
    int j    = idx & 7;
    int lane = (idx >> 3) & 63;
    int kk   = (idx >> 9) & 7;
    int ct   = idx >> 12;
    int n = lane & 15, q = lane >> 4;
    float v = 0.f;
    if (ct < 16) {
        int g = ct * 16 + n;
        int k = kk * 32 + q * 8 + j;
        v = (k < 128) ? Wih[g * 128 + k] : Whh[g * 128 + (k - 128)];
    } else if (ct < 24) {
        if (kk < 4) {
            int g = 256 + (ct - 16) * 16 + n;
            int k = kk * 32 + q * 8 + j;
            v = Wih[g * 128 + k];
        }
    } else {
        if (kk >= 4) {
            int g = 256 + (ct - 24) * 16 + n;
            int k = kk * 32 + q * 8 + j - 128;
            v = Whh[g * 128 + k];
        }
    }
    Wfrag[idx] = f2bf(v);
}

// ---------------------------------------------------------------------------
// Main: persistent-weight MFMA GRU, 16 seqs/block, 512 blocks (2 blocks/CU),
// gate math in C-register layout with v_rcp fast math, 1 barrier/step.
// ---------------------------------------------------------------------------
__global__ __launch_bounds__(NT, 4) void gru_mfma(
    const float* __restrict__ x,      // [8192][32][128]
    const float* __restrict__ h0,     // [8192][128]
    const unsigned short* __restrict__ Wfrag,
    const float* __restrict__ b_ih,   // [384]
    const float* __restrict__ b_hh,   // [384]
    const float* __restrict__ w_out,  // [128]
    const float* __restrict__ b_out,  // [1]
    float* __restrict__ out)          // [8192][32]
{
    __shared__ __align__(16) unsigned short xh[2][MS][XHP];  // bf16 [x | h]
    __shared__ __align__(16) unsigned short wofl[4 * 64 * 8];// W_out B-frags
    __shared__ __align__(16) float outl[MS][OLP];            // per-block out

    const int tid  = threadIdx.x;
    const int n0   = blockIdx.x * MS;
    const int wv   = tid >> 6;       // wave 0..7
    const int lane = tid & 63;
    const int ln   = lane & 15;      // MFMA col (dim-in-tile)
    const int q    = lane >> 4;      // quad (rows q*4..q*4+3)
    const int gn   = (tid >> 4) & 15;// staging: seq 0..15 (tid<256 active)
    const int gd8  = (tid & 15) * 8; // staging: dim 0,8,..,120
    const int d    = wv * 16 + ln;   // this lane's gate dim in [0,128)

    // per-lane biases (registers)
    const float br  = b_ih[d]        + b_hh[d];
    const float bz  = b_ih[DD + d]   + b_hh[DD + d];
    const float bin = b_ih[2*DD + d];
    const float bhn = b_hh[2*DD + d];
    const float bo  = b_out[0];

    // weight fragments -> registers, persistent across the whole t-loop
    bf16x8 wrz0[8], wrz1[8], wxn[4], whn[4];
    {
        const bf16x8* W = (const bf16x8*)Wfrag;
        #pragma unroll
        for (int kk = 0; kk < 8; ++kk) {
            wrz0[kk] = W[((wv    ) * 8 + kk) * 64 + lane];
            wrz1[kk] = W[((wv + 8) * 8 + kk) * 64 + lane];
        }
        #pragma unroll
        for (int kk = 0; kk < 4; ++kk) {
            wxn[kk] = W[((wv + 16) * 8 + kk    ) * 64 + lane];
            whn[kk] = W[((wv + 24) * 8 + kk + 4) * 64 + lane];
        }
    }

    // W_out B-fragment -> LDS (col 0 = w_out, cols 1..15 = 0)
    #pragma unroll
    for (int e = 0; e < 4; ++e) {
        int idx = tid * 4 + e;              // 0..2047
        int j   = idx & 7;
        int l2  = (idx >> 3) & 63;
        int kk  = idx >> 9;                 // 0..3
        int n2 = l2 & 15, q2 = l2 >> 4;
        wofl[idx] = (n2 == 0) ? f2bf(w_out[kk * 32 + q2 * 8 + j])
                              : (unsigned short)0;
    }

    // fp32 hidden state, C-layout: rows q*4+i, dim d
    float hprev[4];
    #pragma unroll
    for (int i = 0; i < 4; ++i)
        hprev[i] = h0[(size_t)(n0 + q*4 + i) * DD + d];

    // prologue: stage h0 (bf16) and x_0 into xh[0]; prefetch x_1, x_2
    const float* xbase = x + ((size_t)(n0 + gn) * LL) * DD + gd8;
    float4 xa0, xa1, xb0, xb1;
    if (tid < 256) {
        const float* hb = h0 + (size_t)(n0 + gn) * DD + gd8;
        pack8(*(const float4*)hb, *(const float4*)(hb + 4), &xh[0][gn][DD + gd8]);
        pack8(*(const float4*)xbase, *(const float4*)(xbase + 4), &xh[0][gn][gd8]);
        xa0 = *(const float4*)(xbase + 1 * DD);
        xa1 = *(const float4*)(xbase + 1 * DD + 4);
        xb0 = *(const float4*)(xbase + 2 * DD);
        xb1 = *(const float4*)(xbase + 2 * DD + 4);
    }
    __syncthreads();

#define GRU_STEP(PAR, XR0, XR1, TCUR, TREFILL)                                 \
    {                                                                          \
        /* stage x_{TCUR+1}; refill prefetch regs for TREFILL */               \
        if (tid < 256) {                                                       \
            pack8(XR0, XR1, &xh[(PAR) ^ 1][gn][gd8]);                          \
            XR0 = *(const float4*)(xbase + (size_t)(TREFILL) * DD);            \
            XR1 = *(const float4*)(xbase + (size_t)(TREFILL) * DD + 4);        \
        }                                                                      \
        /* MFMA: r,z (K=256) + xn/hn (K=128 each) */                           \
        f32x4 c0 = {0.f,0.f,0.f,0.f}, c1 = c0, c2 = c0, c3 = c0;               \
        const unsigned short* xr0 = &xh[PAR][ln][0];                           \
        _Pragma("unroll")                                                      \
        for (int kk = 0; kk < 8; ++kk) {                                       \
            bf16x8 a0 = *(const bf16x8*)(xr0 + kk*32 + q*8);                   \
            c0 = __builtin_amdgcn_mfma_f32_16x16x32_bf16(a0, wrz0[kk], c0,0,0,0); \
            c1 = __builtin_amdgcn_mfma_f32_16x16x32_bf16(a0, wrz1[kk], c1,0,0,0); \
            if (kk < 4) c2 = __builtin_amdgcn_mfma_f32_16x16x32_bf16(a0, wxn[kk],   c2,0,0,0); \
            else        c3 = __builtin_amdgcn_mfma_f32_16x16x32_bf16(a0, whn[kk-4], c3,0,0,0); \
        }                                                                      \
        /* out[t-1] = h_{t-1} . w_out via 4 MFMAs on wave 0 */                 \
        if (wv == 0 && (TCUR) > 0) {                                           \
            f32x4 c4 = {0.f,0.f,0.f,0.f};                                      \
            _Pragma("unroll")                                                  \
            for (int kk = 0; kk < 4; ++kk) {                                   \
                bf16x8 a = *(const bf16x8*)(xr0 + (kk+4)*32 + q*8);            \
                bf16x8 b = *(const bf16x8*)&wofl[(kk*64 + lane)*8];            \
                c4 = __builtin_amdgcn_mfma_f32_16x16x32_bf16(a, b, c4,0,0,0);  \
            }                                                                  \
            if (ln == 0) {                                                     \
                _Pragma("unroll")                                              \
                for (int i = 0; i < 4; ++i)                                    \
                    outl[q*4 + i][(TCUR)-1] = c4[i] + bo;                      \
            }                                                                  \
        }                                                                      \
        /* gate math in C-register layout, v_rcp fast divides */               \
        _Pragma("unroll")                                                      \
        for (int i = 0; i < 4; ++i) {                                          \
            const float rr = fast_rcp(1.f + __expf(-(c0[i] + br)));            \
            const float zz = fast_rcp(1.f + __expf(-(c1[i] + bz)));            \
            float aa = c2[i] + bin + rr * (c3[i] + bhn);                       \
            aa = fminf(fmaxf(aa, -20.f), 20.f);                                \
            const float ee = __expf(-2.f * aa);                                \
            const float th = (1.f - ee) * fast_rcp(1.f + ee);                  \
            const float hh = th + zz * (hprev[i] - th);                        \
            hprev[i] = hh;                                                     \
            xh[(PAR) ^ 1][q*4 + i][DD + d] = f2bf(hh);                         \
        }                                                                      \
        __syncthreads();                                                       \
    }

    for (int t = 0; t < LL; t += 2) {
        const int r0 = (t + 3 < LL) ? t + 3 : LL - 1;
        const int r1 = (t + 4 < LL) ? t + 4 : LL - 1;
        GRU_STEP(0, xa0, xa1, t,     r0)
        GRU_STEP(1, xb0, xb1, t + 1, r1)
    }
#undef GRU_STEP

    // final output column: out_31 = h_31 . w_out (h_31 lives in xh[0] h-region)
    if (wv == 0) {
        f32x4 c4 = {0.f,0.f,0.f,0.f};
        const unsigned short* xr = &xh[0][ln][0];
        #pragma unroll
        for (int kk = 0; kk < 4; ++kk) {
            bf16x8 a = *(const bf16x8*)(xr + (kk+4)*32 + q*8);
            bf16x8 b = *(const bf16x8*)&wofl[(kk*64 + lane)*8];
            c4 = __builtin_amdgcn_mfma_f32_16x16x32_bf16(a, b, c4,0,0,0);
        }
        if (ln == 0) {
            #pragma unroll
            for (int i = 0; i < 4; ++i)
                outl[q*4 + i][LL-1] = c4[i] + bo;
        }
    }
    __syncthreads();

    // coalesced flush: block's 16x32 outputs are contiguous in global
    if (tid < 128) {
        const int row = tid >> 3;
        const int t4  = (tid & 7) * 4;
        float4 v = *(const float4*)&outl[row][t4];
        *(float4*)(out + (size_t)(n0 + row) * LL + t4) = v;
    }
}

extern "C" void kernel_launch(void* const* d_in, const int* in_sizes, int n_in,
                              void* d_out, int out_size, void* d_ws, size_t ws_size,
                              hipStream_t stream) {
    const float* item  = (const float*)d_in[0];
    const float* user  = (const float*)d_in[1];
    const float* W_ih  = (const float*)d_in[2];
    const float* W_hh  = (const float*)d_in[3];
    const float* b_ih  = (const float*)d_in[4];
    const float* b_hh  = (const float*)d_in[5];
    const float* W_out = (const float*)d_in[6];
    const float* b_out = (const float*)d_in[7];
    float* out = (float*)d_out;

    unsigned short* Wfrag = (unsigned short*)d_ws;   // 32*8*64*8 = 131072 bf16

    prep_weights<<<512, 256, 0, stream>>>(W_ih, W_hh, Wfrag);
    gru_mfma<<<NSEQ / MS, NT, 0, stream>>>(item, user, Wfrag,
                                           b_ih, b_hh, W_out, b_out, out);
}

// Round 6
// 223.001 us; speedup vs baseline: 1.8184x; 1.8184x over previous
//
#include <hip/hip_runtime.h>
#include <math.h>

#define DD   128      // hidden dim
#define LL   32       // sequence length
#define MS   32       // sequences per block
#define NT   512      // threads per block (8 waves)
#define NSEQ 8192     // B*S
#define XHP  264      // xh row pitch in ushorts (256 data + 8 pad; 528 B)
#define OLP  36       // outl pitch in floats

typedef short bf16x8 __attribute__((ext_vector_type(8)));   // 8 bf16 = 4 VGPRs
typedef float f32x4  __attribute__((ext_vector_type(4)));

__device__ __forceinline__ unsigned short f2bf(float f) {
    unsigned u = __float_as_uint(f);
    u += 0x7fffu + ((u >> 16) & 1u);          // round-to-nearest-even
    return (unsigned short)(u >> 16);
}

#if __has_builtin(__builtin_amdgcn_cvt_pk_bf16_f32)
typedef __bf16 bf16x2_t __attribute__((ext_vector_type(2)));
__device__ __forceinline__ unsigned pack2(float a, float b) {
    union { bf16x2_t v; unsigned u; } c;
    c.v = __builtin_amdgcn_cvt_pk_bf16_f32(a, b);
    return c.u;
}
#else
__device__ __forceinline__ unsigned pack2(float a, float b) {
    return (unsigned)f2bf(a) | ((unsigned)f2bf(b) << 16);
}
#endif

__device__ __forceinline__ void pack8(float4 a, float4 b, unsigned short* dst) {
    union { unsigned u[4]; bf16x8 v; } pk;
    pk.u[0] = pack2(a.x, a.y); pk.u[1] = pack2(a.z, a.w);
    pk.u[2] = pack2(b.x, b.y); pk.u[3] = pack2(b.z, b.w);
    *(bf16x8*)dst = pk.v;
}

__device__ __forceinline__ float fast_rcp(float x) {
    return __builtin_amdgcn_rcpf(x);   // v_rcp_f32, ~1 ulp — fine at bf16 output
}

// ---------------------------------------------------------------------------
// Prep: swizzle W_ih/W_hh into MFMA B-operand fragment order, bf16.
//   ct 0..15 : r,z gates  g=ct*16+n,        k=kk*32+q*8+j (K=256 concat x|h)
//   ct 16..23: n-gate x-side, kk 0..3, k in [0,128)   (W_ih)
//   ct 24..31: n-gate h-side, kk 4..7, k-128 in [0,128) (W_hh)
// ---------------------------------------------------------------------------
__global__ void prep_weights(const float* __restrict__ Wih,
                             const float* __restrict__ Whh,
                             unsigned short* __restrict__ Wfrag) {
    int idx = blockIdx.x * blockDim.x + threadIdx.x;   // 0 .. 131071
    int j    = idx & 7;
    int lane = (idx >> 3) & 63;
    int kk   = (idx >> 9) & 7;
    int ct   = idx >> 12;
    int n = lane & 15, q = lane >> 4;
    float v = 0.f;
    if (ct < 16) {
        int g = ct * 16 + n;
        int k = kk * 32 + q * 8 + j;
        v = (k < 128) ? Wih[g * 128 + k] : Whh[g * 128 + (k - 128)];
    } else if (ct < 24) {
        if (kk < 4) {
            int g = 256 + (ct - 16) * 16 + n;
            int k = kk * 32 + q * 8 + j;
            v = Wih[g * 128 + k];
        }
    } else {
        if (kk >= 4) {
            int g = 256 + (ct - 24) * 16 + n;
            int k = kk * 32 + q * 8 + j - 128;
            v = Whh[g * 128 + k];
        }
    }
    Wfrag[idx] = f2bf(v);
}

// ---------------------------------------------------------------------------
// Main: persistent-weight MFMA GRU, 32 seqs/block (two 16-row tiles/wave),
// gate math in C-register layout with v_rcp fast math, one barrier per step.
// NOTE: min-waves MUST stay at 2 — launch_bounds(512,4) caps VGPR<=128 and
// spills the persistent weight fragments to scratch (round-5: 780MB FETCH).
// ---------------------------------------------------------------------------
__global__ __launch_bounds__(NT, 2) void gru_mfma(
    const float* __restrict__ x,      // [8192][32][128]
    const float* __restrict__ h0,     // [8192][128]
    const unsigned short* __restrict__ Wfrag,
    const float* __restrict__ b_ih,   // [384]
    const float* __restrict__ b_hh,   // [384]
    const float* __restrict__ w_out,  // [128]
    const float* __restrict__ b_out,  // [1]
    float* __restrict__ out)          // [8192][32]
{
    __shared__ __align__(16) unsigned short xh[2][MS][XHP];  // bf16 [x | h]
    __shared__ __align__(16) unsigned short wofl[4 * 64 * 8];// W_out B-frags
    __shared__ __align__(16) float outl[MS][OLP];            // per-block out

    const int tid  = threadIdx.x;
    const int n0   = blockIdx.x * MS;
    const int wv   = tid >> 6;       // wave 0..7
    const int lane = tid & 63;
    const int ln   = lane & 15;      // MFMA col (dim-in-tile)
    const int q    = lane >> 4;      // quad (rows q*4..q*4+3)
    const int gn   = tid >> 4;       // staging: seq 0..31
    const int gd8  = (tid & 15) * 8; // staging: dim 0,8,..,120
    const int d    = wv * 16 + ln;   // this lane's gate dim in [0,128)

    // per-lane biases (registers)
    const float br  = b_ih[d]        + b_hh[d];
    const float bz  = b_ih[DD + d]   + b_hh[DD + d];
    const float bin = b_ih[2*DD + d];
    const float bhn = b_hh[2*DD + d];
    const float bo  = b_out[0];

    // weight fragments -> registers, persistent across the whole t-loop
    bf16x8 wrz0[8], wrz1[8], wxn[4], whn[4];
    {
        const bf16x8* W = (const bf16x8*)Wfrag;
        #pragma unroll
        for (int kk = 0; kk < 8; ++kk) {
            wrz0[kk] = W[((wv    ) * 8 + kk) * 64 + lane];
            wrz1[kk] = W[((wv + 8) * 8 + kk) * 64 + lane];
        }
        #pragma unroll
        for (int kk = 0; kk < 4; ++kk) {
            wxn[kk] = W[((wv + 16) * 8 + kk    ) * 64 + lane];
            whn[kk] = W[((wv + 24) * 8 + kk + 4) * 64 + lane];
        }
    }

    // W_out B-fragment -> LDS (col 0 = w_out, cols 1..15 = 0)
    #pragma unroll
    for (int e = 0; e < 4; ++e) {
        int idx = tid * 4 + e;              // 0..2047
        int j   = idx & 7;
        int l2  = (idx >> 3) & 63;
        int kk  = idx >> 9;                 // 0..3
        int n2 = l2 & 15, q2 = l2 >> 4;
        wofl[idx] = (n2 == 0) ? f2bf(w_out[kk * 32 + q2 * 8 + j])
                              : (unsigned short)0;
    }

    // fp32 hidden state, C-layout: tile tl rows tl*16+q*4+i, dim d
    float hprev[8];
    #pragma unroll
    for (int tl = 0; tl < 2; ++tl)
        #pragma unroll
        for (int i = 0; i < 4; ++i)
            hprev[tl*4+i] = h0[(size_t)(n0 + tl*16 + q*4 + i) * DD + d];

    // prologue: stage h0 (bf16) and x_0 into xh[0]; prefetch x_1, x_2
    {
        const float* hb = h0 + (size_t)(n0 + gn) * DD + gd8;
        pack8(*(const float4*)hb, *(const float4*)(hb + 4), &xh[0][gn][DD + gd8]);
    }
    const float* xbase = x + ((size_t)(n0 + gn) * LL) * DD + gd8;
    pack8(*(const float4*)xbase, *(const float4*)(xbase + 4), &xh[0][gn][gd8]);
    float4 xa0 = *(const float4*)(xbase + 1 * DD);
    float4 xa1 = *(const float4*)(xbase + 1 * DD + 4);
    float4 xb0 = *(const float4*)(xbase + 2 * DD);
    float4 xb1 = *(const float4*)(xbase + 2 * DD + 4);
    __syncthreads();

#define GRU_STEP(PAR, XR0, XR1, TCUR, TREFILL)                                 \
    {                                                                          \
        /* stage x_{TCUR+1}; refill prefetch regs for TREFILL */               \
        pack8(XR0, XR1, &xh[(PAR) ^ 1][gn][gd8]);                              \
        XR0 = *(const float4*)(xbase + (size_t)(TREFILL) * DD);                \
        XR1 = *(const float4*)(xbase + (size_t)(TREFILL) * DD + 4);            \
        /* MFMA: two 16-row tiles, r,z (K=256) + xn/hn (K=128 each) */         \
        f32x4 c0[2], c1[2], c2[2], c3[2];                                      \
        _Pragma("unroll")                                                      \
        for (int tl = 0; tl < 2; ++tl) {                                       \
            c0[tl] = (f32x4){0.f,0.f,0.f,0.f}; c1[tl] = c0[tl];                \
            c2[tl] = c0[tl]; c3[tl] = c0[tl];                                  \
        }                                                                      \
        const unsigned short* xr0 = &xh[PAR][ln][0];                           \
        const unsigned short* xr1 = &xh[PAR][16 + ln][0];                      \
        _Pragma("unroll")                                                      \
        for (int kk = 0; kk < 8; ++kk) {                                       \
            bf16x8 a0 = *(const bf16x8*)(xr0 + kk*32 + q*8);                   \
            bf16x8 a1 = *(const bf16x8*)(xr1 + kk*32 + q*8);                   \
            c0[0] = __builtin_amdgcn_mfma_f32_16x16x32_bf16(a0, wrz0[kk], c0[0],0,0,0); \
            c0[1] = __builtin_amdgcn_mfma_f32_16x16x32_bf16(a1, wrz0[kk], c0[1],0,0,0); \
            c1[0] = __builtin_amdgcn_mfma_f32_16x16x32_bf16(a0, wrz1[kk], c1[0],0,0,0); \
            c1[1] = __builtin_amdgcn_mfma_f32_16x16x32_bf16(a1, wrz1[kk], c1[1],0,0,0); \
            if (kk < 4) {                                                      \
                c2[0] = __builtin_amdgcn_mfma_f32_16x16x32_bf16(a0, wxn[kk], c2[0],0,0,0); \
                c2[1] = __builtin_amdgcn_mfma_f32_16x16x32_bf16(a1, wxn[kk], c2[1],0,0,0); \
            } else {                                                           \
                c3[0] = __builtin_amdgcn_mfma_f32_16x16x32_bf16(a0, whn[kk-4], c3[0],0,0,0); \
                c3[1] = __builtin_amdgcn_mfma_f32_16x16x32_bf16(a1, whn[kk-4], c3[1],0,0,0); \
            }                                                                  \
        }                                                                      \
        /* out[t-1] = h_{t-1} . w_out via MFMA on waves 0/1 (tile = wv) */     \
        if (wv < 2 && (TCUR) > 0) {                                            \
            f32x4 c4 = {0.f,0.f,0.f,0.f};                                      \
            const unsigned short* xr = (wv == 0) ? xr0 : xr1;                  \
            _Pragma("unroll")                                                  \
            for (int kk = 0; kk < 4; ++kk) {                                   \
                bf16x8 a = *(const bf16x8*)(xr + (kk+4)*32 + q*8);             \
                bf16x8 b = *(const bf16x8*)&wofl[(kk*64 + lane)*8];            \
                c4 = __builtin_amdgcn_mfma_f32_16x16x32_bf16(a, b, c4,0,0,0);  \
            }                                                                  \
            if (ln == 0) {                                                     \
                _Pragma("unroll")                                              \
                for (int i = 0; i < 4; ++i)                                    \
                    outl[wv*16 + q*4 + i][(TCUR)-1] = c4[i] + bo;              \
            }                                                                  \
        }                                                                      \
        /* gate math in C-register layout, v_rcp fast divides */               \
        _Pragma("unroll")                                                      \
        for (int tl = 0; tl < 2; ++tl) {                                       \
            _Pragma("unroll")                                                  \
            for (int i = 0; i < 4; ++i) {                                      \
                const float rr = fast_rcp(1.f + __expf(-(c0[tl][i] + br)));    \
                const float zz = fast_rcp(1.f + __expf(-(c1[tl][i] + bz)));    \
                float aa = c2[tl][i] + bin + rr * (c3[tl][i] + bhn);           \
                aa = fminf(fmaxf(aa, -20.f), 20.f);                            \
                const float ee = __expf(-2.f * aa);                            \
                const float th = (1.f - ee) * fast_rcp(1.f + ee);              \
                const float hh = th + zz * (hprev[tl*4+i] - th);               \
                hprev[tl*4+i] = hh;                                            \
                xh[(PAR) ^ 1][tl*16 + q*4 + i][DD + d] = f2bf(hh);             \
            }                                                                  \
        }                                                                      \
        __syncthreads();                                                       \
    }

    for (int t = 0; t < LL; t += 2) {
        const int r0 = (t + 3 < LL) ? t + 3 : LL - 1;
        const int r1 = (t + 4 < LL) ? t + 4 : LL - 1;
        GRU_STEP(0, xa0, xa1, t,     r0)
        GRU_STEP(1, xb0, xb1, t + 1, r1)
    }
#undef GRU_STEP

    // final output column: out_31 = h_31 . w_out (h_31 lives in xh[0] h-region)
    if (wv < 2) {
        f32x4 c4 = {0.f,0.f,0.f,0.f};
        const unsigned short* xr = &xh[0][wv*16 + ln][0];
        #pragma unroll
        for (int kk = 0; kk < 4; ++kk) {
            bf16x8 a = *(const bf16x8*)(xr + (kk+4)*32 + q*8);
            bf16x8 b = *(const bf16x8*)&wofl[(kk*64 + lane)*8];
            c4 = __builtin_amdgcn_mfma_f32_16x16x32_bf16(a, b, c4,0,0,0);
        }
        if (ln == 0) {
            #pragma unroll
            for (int i = 0; i < 4; ++i)
                outl[wv*16 + q*4 + i][LL-1] = c4[i] + bo;
        }
    }
    __syncthreads();

    // coalesced flush: block's 32x32 outputs are contiguous in global
    if (tid < 256) {
        const int row = tid >> 3;
        const int t4  = (tid & 7) * 4;
        float4 v = *(const float4*)&outl[row][t4];
        *(float4*)(out + (size_t)(n0 + row) * LL + t4) = v;
    }
}

extern "C" void kernel_launch(void* const* d_in, const int* in_sizes, int n_in,
                              void* d_out, int out_size, void* d_ws, size_t ws_size,
                              hipStream_t stream) {
    const float* item  = (const float*)d_in[0];
    const float* user  = (const float*)d_in[1];
    const float* W_ih  = (const float*)d_in[2];
    const float* W_hh  = (const float*)d_in[3];
    const float* b_ih  = (const float*)d_in[4];
    const float* b_hh  = (const float*)d_in[5];
    const float* W_out = (const float*)d_in[6];
    const float* b_out = (const float*)d_in[7];
    float* out = (float*)d_out;

    unsigned short* Wfrag = (unsigned short*)d_ws;   // 32*8*64*8 = 131072 bf16

    prep_weights<<<512, 256, 0, stream>>>(W_ih, W_hh, Wfrag);
    gru_mfma<<<NSEQ / MS, NT, 0, stream>>>(item, user, Wfrag,
                                           b_ih, b_hh, W_out, b_out, out);
}